// Round 9
// baseline (173.058 us; speedup 1.0000x reference)
//
#include <hip/hip_runtime.h>
#include <hip/hip_bf16.h>

#define TROWS 1048576
#define RPB   256                    // rows per block (chunk)
#define NCHUNK (TROWS / RPB)         // 4096
#define LSTRIDE 36                   // out0 LDS row stride in shorts (72 B)

typedef float f32x4  __attribute__((ext_vector_type(4)));
typedef short bf16x8 __attribute__((ext_vector_type(8)));
typedef short bf16x4 __attribute__((ext_vector_type(4)));

#define MFMA(a, b, c) __builtin_amdgcn_mfma_f32_16x16x32_bf16(a, b, c, 0, 0, 0)

__device__ __forceinline__ short f2bf(float v) {
    __hip_bfloat16 b = __float2bfloat16(v);
    return __builtin_bit_cast(short, b);
}
__device__ __forceinline__ float bf2f(short s) {
    unsigned u = ((unsigned)(unsigned short)s) << 16;
    return __builtin_bit_cast(float, u);
}

// k-map for ALL A/B fragments: kappa(g,j) = j<4 ? 4g+j : 16+4g+(j-4)
// ---------------------------------------------------------------------------
// Prep: weights -> bf16 fragment order (verified rounds 2-8).
//   W0a: frag 0..15 (ks*8+nt)   W0b: 16..23 (k2*2+ot)
//   W1a: 24..47 (ks*8+nt)       W1b: 48..55 (k2*2+ot)
// ---------------------------------------------------------------------------
__global__ __launch_bounds__(64) void prep_kernel(
    const float* __restrict__ W0a, const float* __restrict__ W0b,
    const float* __restrict__ W1a, const float* __restrict__ W1b,
    bf16x8* __restrict__ frag)
{
    const int fid = blockIdx.x, l = threadIdx.x, c = l & 15, g = l >> 4;
    const float* W; int N, ks, nt;
    if (fid < 16)      { W = W0a; N = 128; ks = fid >> 3;        nt = fid & 7; }
    else if (fid < 24) { W = W0b; N = 32;  ks = (fid - 16) >> 1; nt = (fid - 16) & 1; }
    else if (fid < 48) { W = W1a; N = 128; ks = (fid - 24) >> 3; nt = (fid - 24) & 7; }
    else               { W = W1b; N = 32;  ks = (fid - 48) >> 1; nt = (fid - 48) & 1; }
    bf16x8 f;
    #pragma unroll
    for (int j = 0; j < 8; ++j) {
        const int k = 32 * ks + ((j < 4) ? (4 * g + j) : (16 + 4 * g + (j - 4)));
        f[j] = f2bf(W[k * N + 16 * nt + c]);
    }
    frag[fid * 64 + l] = f;
}

// ---------------------------------------------------------------------------
// Fused kernel (r7 shape): 4 waves / 256 rows. LDS weights (W0 24KB -> W1
// 32KB union). NEW vs r7: (1) T14 W1 reg-prefetch issued right after B1,
// consumed after B2 (hides L2 latency under phase A); (2) tile-order topk/wts
// via __shfl from tid-order regs (kills 12 VMEM/wave); (3) blend uses fp32
// acc2a regs for own out0 (no LDS re-read); (4) s_setprio around MFMA phases.
// ---------------------------------------------------------------------------
__global__ __launch_bounds__(256, 3) void fused_kernel(
    const float* __restrict__ x, const int* __restrict__ topk,
    const float* __restrict__ wts,
    const float* __restrict__ b0a, const float* __restrict__ b0b,
    const float* __restrict__ b1a, const float* __restrict__ b1b,
    const bf16x8* __restrict__ frag,
    float* __restrict__ out)
{
    const int b = blockIdx.x;
    const int bb = b * RPB;
    const int tid = threadIdx.x, wv = tid >> 6, l = tid & 63, c = l & 15, g = l >> 4;

    __shared__ __align__(16) short frag_lds[32 * 64 * 8];    // 32 KB
    __shared__ __align__(16) short out0_lds[257 * LSTRIDE];  // 18.5 KB
    __shared__ int wtot[4];

    #define LDSF(fl) (*(const bf16x8*)&frag_lds[(((fl) * 64) + l) * 8])

    // --- stage W0 frags (fid 0..23 -> local 0..23): 24KB, 6 x 16B/thread ---
    #pragma unroll
    for (int i = 0; i < 6; ++i) {
        const int e = tid + i * 256;      // e < 1536
        *(f32x4*)&frag_lds[e * 8] = *(const f32x4*)&frag[e];
    }

    // --- own-row tid-order loads: topk masks + weight (shuffled later) ---
    const int t = bb + tid;
    const int2 tko = ((const int2*)topk)[t];
    const bool m0o = (tko.x == 0) || (tko.y == 0);
    const bool m1o = (tko.x == 1) || (tko.y == 1);
    const int  mo_own  = (m0o ? 1 : 0) | (m1o ? 2 : 0);
    const float wgt_own = wts[(size_t)t * 2];

    // --- wave-local inclusive cummax of (mask0 ? t : 0) ---
    int s = m0o ? t : 0;
    #pragma unroll
    for (int off = 1; off < 64; off <<= 1) {
        int u = __shfl_up(s, off, 64);
        if (l >= off) s = max(s, u);
    }
    if (l == 63) wtot[wv] = s;

    // --- backward scan for p = last mask0 row < bb (input-only) ---
    int p = 0;
    for (int base = bb - 64; base >= 0; base -= 64) {
        const int2 tkq = ((const int2*)topk)[base + l];
        const bool mm = (tkq.x == 0) || (tkq.y == 0);
        const unsigned long long bal = __ballot(mm);
        if (bal) { p = base + 63 - __clzll(bal); break; }
    }
    const int2 tkp = ((const int2*)topk)[p];
    const bool m0p = (tkp.x == 0) || (tkp.y == 0);

    // --- x fragments: own 4 tiles (+ p-row on wave 3), the only x reads ---
    bf16x8 xf[4][2];
    #pragma unroll
    for (int rt = 0; rt < 4; ++rt) {
        const int row = bb + wv * 64 + rt * 16 + c;
        const float* xr = x + (size_t)row * 64;
        #pragma unroll
        for (int ks = 0; ks < 2; ++ks) {
            f32x4 a  = *(const f32x4*)(xr + 32 * ks + 4 * g);
            f32x4 b2 = *(const f32x4*)(xr + 32 * ks + 16 + 4 * g);
            #pragma unroll
            for (int j = 0; j < 4; ++j) { xf[rt][ks][j] = f2bf(a[j]); xf[rt][ks][4 + j] = f2bf(b2[j]); }
        }
    }
    bf16x8 xfp[2];
    if (wv == 3) {
        const float* xp = x + (size_t)p * 64;
        #pragma unroll
        for (int ks = 0; ks < 2; ++ks) {
            f32x4 a  = *(const f32x4*)(xp + 32 * ks + 4 * g);
            f32x4 b2 = *(const f32x4*)(xp + 32 * ks + 16 + 4 * g);
            #pragma unroll
            for (int j = 0; j < 4; ++j) { xfp[ks][j] = f2bf(a[j]); xfp[ks][4 + j] = f2bf(b2[j]); }
        }
    }

    __syncthreads();   // B1: W0 staged; wtot visible

    // --- T14: issue W1 frag loads NOW (consumed after B2). 32KB = 8 x 16B/thr ---
    f32x4 w1pre[8];
    #pragma unroll
    for (int i = 0; i < 8; ++i)
        w1pre[i] = *(const f32x4*)&frag[24 * 64 + tid + i * 256];

    // --- per-row global inclusive cummax ---
    int pre = 0;
    #pragma unroll
    for (int w2 = 0; w2 < 4; ++w2)
        if (w2 < wv) pre = max(pre, wtot[w2]);
    const int s_full = max(pre, s);

    // ---- phase A: MLP0, k2-outer (frags ds_read once, 4 tiles share) ----
    f32x4 acc2a[4][2];
    {
        f32x4 bi0 = *(const f32x4*)(b0b + 4 * g);
        f32x4 bi1 = *(const f32x4*)(b0b + 16 + 4 * g);
        #pragma unroll
        for (int rt = 0; rt < 4; ++rt) { acc2a[rt][0] = bi0; acc2a[rt][1] = bi1; }
    }
    __builtin_amdgcn_s_setprio(1);
    #pragma unroll
    for (int k2 = 0; k2 < 4; ++k2) {
        const bf16x8 fa00 = LDSF(0 * 8 + 2 * k2 + 0);
        const bf16x8 fa01 = LDSF(0 * 8 + 2 * k2 + 1);
        const bf16x8 fa10 = LDSF(1 * 8 + 2 * k2 + 0);
        const bf16x8 fa11 = LDSF(1 * 8 + 2 * k2 + 1);
        const bf16x8 fb0  = LDSF(16 + 2 * k2 + 0);
        const bf16x8 fb1  = LDSF(16 + 2 * k2 + 1);
        const f32x4 bi0 = *(const f32x4*)(b0a + 16 * (2 * k2 + 0) + 4 * g);
        const f32x4 bi1 = *(const f32x4*)(b0a + 16 * (2 * k2 + 1) + 4 * g);
        #pragma unroll
        for (int rt = 0; rt < 4; ++rt) {
            f32x4 a10 = bi0, a11 = bi1;
            a10 = MFMA(fa00, xf[rt][0], a10);
            a10 = MFMA(fa10, xf[rt][1], a10);
            a11 = MFMA(fa01, xf[rt][0], a11);
            a11 = MFMA(fa11, xf[rt][1], a11);
            bf16x8 hf;
            #pragma unroll
            for (int j = 0; j < 8; ++j)
                hf[j] = f2bf(fmaxf((j < 4 ? a10 : a11)[j & 3], 0.0f));
            acc2a[rt][0] = MFMA(fb0, hf, acc2a[rt][0]);
            acc2a[rt][1] = MFMA(fb1, hf, acc2a[rt][1]);
        }
    }
    __builtin_amdgcn_s_setprio(0);

    // --- store own tiles (masked, via shuffled mask) to out0 LDS ---
    #pragma unroll
    for (int rt = 0; rt < 4; ++rt) {
        const int slot = wv * 64 + rt * 16 + c;
        const bool m0 = (__shfl(mo_own, rt * 16 + c, 64) & 1);
        #pragma unroll
        for (int ot = 0; ot < 2; ++ot) {
            bf16x4 v;
            #pragma unroll
            for (int j = 0; j < 4; ++j) v[j] = f2bf(m0 ? acc2a[rt][ot][j] : 0.0f);
            *(bf16x4*)(&out0_lds[slot * LSTRIDE + 16 * ot + 4 * g]) = v;
        }
    }

    // --- wave 3: p-row tile -> slot 256 ---
    if (wv == 3) {
        f32x4 accp[2];
        accp[0] = *(const f32x4*)(b0b + 4 * g);
        accp[1] = *(const f32x4*)(b0b + 16 + 4 * g);
        #pragma unroll
        for (int k2 = 0; k2 < 4; ++k2) {
            const bf16x8 fa00 = LDSF(0 * 8 + 2 * k2 + 0);
            const bf16x8 fa01 = LDSF(0 * 8 + 2 * k2 + 1);
            const bf16x8 fa10 = LDSF(1 * 8 + 2 * k2 + 0);
            const bf16x8 fa11 = LDSF(1 * 8 + 2 * k2 + 1);
            const bf16x8 fb0  = LDSF(16 + 2 * k2 + 0);
            const bf16x8 fb1  = LDSF(16 + 2 * k2 + 1);
            f32x4 a10 = *(const f32x4*)(b0a + 16 * (2 * k2 + 0) + 4 * g);
            f32x4 a11 = *(const f32x4*)(b0a + 16 * (2 * k2 + 1) + 4 * g);
            a10 = MFMA(fa00, xfp[0], a10);
            a10 = MFMA(fa10, xfp[1], a10);
            a11 = MFMA(fa01, xfp[0], a11);
            a11 = MFMA(fa11, xfp[1], a11);
            bf16x8 hf;
            #pragma unroll
            for (int j = 0; j < 8; ++j)
                hf[j] = f2bf(fmaxf((j < 4 ? a10 : a11)[j & 3], 0.0f));
            accp[0] = MFMA(fb0, hf, accp[0]);
            accp[1] = MFMA(fb1, hf, accp[1]);
        }
        if (c == 0) {
            #pragma unroll
            for (int ot = 0; ot < 2; ++ot) {
                bf16x4 v;
                #pragma unroll
                for (int j = 0; j < 4; ++j) v[j] = f2bf(m0p ? accp[ot][j] : 0.0f);
                *(bf16x4*)(&out0_lds[256 * LSTRIDE + 16 * ot + 4 * g]) = v;
            }
        }
    }

    __syncthreads();   // B2: out0 complete; all W0 frag reads done

    // --- write W1 frags from prefetch registers (loads landed during A) ---
    #pragma unroll
    for (int i = 0; i < 8; ++i)
        *(f32x4*)&frag_lds[(tid + i * 256) * 8] = w1pre[i];

    __syncthreads();   // B3: W1 frags staged

    // --- gather filled frags via s_full ---
    bf16x8 xf2[4];
    #pragma unroll
    for (int rt = 0; rt < 4; ++rt) {
        const int sF = __shfl(s_full, rt * 16 + c, 64);
        const int slot = (sF > 0) ? (sF - bb) : 256;
        const short* fr = &out0_lds[slot * LSTRIDE];
        bf16x4 fa_ = *(const bf16x4*)(fr + 4 * g);
        bf16x4 fb_ = *(const bf16x4*)(fr + 16 + 4 * g);
        #pragma unroll
        for (int j = 0; j < 4; ++j) { xf2[rt][j] = fa_[j]; xf2[rt][4 + j] = fb_[j]; }
    }

    // ---- phase B: MLP1, k2-outer ----
    f32x4 acc2b[4][2];
    {
        f32x4 bi0 = *(const f32x4*)(b1b + 4 * g);
        f32x4 bi1 = *(const f32x4*)(b1b + 16 + 4 * g);
        #pragma unroll
        for (int rt = 0; rt < 4; ++rt) { acc2b[rt][0] = bi0; acc2b[rt][1] = bi1; }
    }
    __builtin_amdgcn_s_setprio(1);
    #pragma unroll
    for (int k2 = 0; k2 < 4; ++k2) {
        const bf16x8 fa00 = LDSF(0 * 8 + 2 * k2 + 0);   // W1a local 0..23
        const bf16x8 fa01 = LDSF(0 * 8 + 2 * k2 + 1);
        const bf16x8 fa10 = LDSF(1 * 8 + 2 * k2 + 0);
        const bf16x8 fa11 = LDSF(1 * 8 + 2 * k2 + 1);
        const bf16x8 fa20 = LDSF(2 * 8 + 2 * k2 + 0);
        const bf16x8 fa21 = LDSF(2 * 8 + 2 * k2 + 1);
        const bf16x8 fb0  = LDSF(24 + 2 * k2 + 0);      // W1b local 24..31
        const bf16x8 fb1  = LDSF(24 + 2 * k2 + 1);
        const f32x4 bi0 = *(const f32x4*)(b1a + 16 * (2 * k2 + 0) + 4 * g);
        const f32x4 bi1 = *(const f32x4*)(b1a + 16 * (2 * k2 + 1) + 4 * g);
        #pragma unroll
        for (int rt = 0; rt < 4; ++rt) {
            f32x4 a10 = bi0, a11 = bi1;
            a10 = MFMA(fa00, xf[rt][0], a10);
            a10 = MFMA(fa10, xf[rt][1], a10);
            a10 = MFMA(fa20, xf2[rt], a10);
            a11 = MFMA(fa01, xf[rt][0], a11);
            a11 = MFMA(fa11, xf[rt][1], a11);
            a11 = MFMA(fa21, xf2[rt], a11);
            bf16x8 hf;
            #pragma unroll
            for (int j = 0; j < 8; ++j)
                hf[j] = f2bf(fmaxf((j < 4 ? a10 : a11)[j & 3], 0.0f));
            acc2b[rt][0] = MFMA(fb0, hf, acc2b[rt][0]);
            acc2b[rt][1] = MFMA(fb1, hf, acc2b[rt][1]);
        }
    }
    __builtin_amdgcn_s_setprio(0);

    // --- blend + store: own out0 from fp32 regs (no LDS re-read) ---
    #pragma unroll
    for (int rt = 0; rt < 4; ++rt) {
        const int row = bb + wv * 64 + rt * 16 + c;
        const int mo = __shfl(mo_own, rt * 16 + c, 64);
        const float w  = __shfl(wgt_own, rt * 16 + c, 64);
        const float wc = 1.0f - w;
        const bool m0 = mo & 1, m1 = mo & 2;
        #pragma unroll
        for (int ot = 0; ot < 2; ++ot) {
            f32x4 r;
            #pragma unroll
            for (int j = 0; j < 4; ++j) {
                const float e0 = m0 ? acc2a[rt][ot][j] : 0.0f;
                const float e1 = m1 ? acc2b[rt][ot][j] : 0.0f;
                r[j] = w * e0 + wc * e1;
            }
            *(f32x4*)(out + (size_t)row * 32 + 16 * ot + 4 * g) = r;
        }
    }
    #undef LDSF
}

// ---------------------------------------------------------------------------
extern "C" void kernel_launch(void* const* d_in, const int* in_sizes, int n_in,
                              void* d_out, int out_size, void* d_ws, size_t ws_size,
                              hipStream_t stream)
{
    const float* x    = (const float*)d_in[0];
    const int*   topk = (const int*)  d_in[1];
    const float* wts  = (const float*)d_in[2];
    const float* W0a  = (const float*)d_in[3];
    const float* b0a  = (const float*)d_in[4];
    const float* W0b  = (const float*)d_in[5];
    const float* b0b  = (const float*)d_in[6];
    const float* W1a  = (const float*)d_in[7];
    const float* b1a  = (const float*)d_in[8];
    const float* W1b  = (const float*)d_in[9];
    const float* b1b  = (const float*)d_in[10];
    float* out = (float*)d_out;

    bf16x8* frag = (bf16x8*)d_ws;   // 56 KiB

    prep_kernel<<<dim3(56), dim3(64), 0, stream>>>(W0a, W0b, W1a, W1b, frag);
    fused_kernel<<<dim3(NCHUNK), dim3(256), 0, stream>>>(
        x, topk, wts, b0a, b0b, b1a, b1b, frag, out);
}

// Round 10
// 155.178 us; speedup vs baseline: 1.1152x; 1.1152x over previous
//
#include <hip/hip_runtime.h>
#include <hip/hip_bf16.h>

#define TROWS 1048576
#define RPB   256                    // rows per block (chunk)
#define NCHUNK (TROWS / RPB)         // 4096
#define LSTRIDE 36                   // out0 LDS row stride in shorts (72 B)

typedef float f32x4  __attribute__((ext_vector_type(4)));
typedef short bf16x8 __attribute__((ext_vector_type(8)));
typedef short bf16x4 __attribute__((ext_vector_type(4)));

#define MFMA(a, b, c) __builtin_amdgcn_mfma_f32_16x16x32_bf16(a, b, c, 0, 0, 0)

__device__ __forceinline__ short f2bf(float v) {
    __hip_bfloat16 b = __float2bfloat16(v);
    return __builtin_bit_cast(short, b);
}
__device__ __forceinline__ float bf2f(short s) {
    unsigned u = ((unsigned)(unsigned short)s) << 16;
    return __builtin_bit_cast(float, u);
}

// k-map for ALL A/B fragments: kappa(g,j) = j<4 ? 4g+j : 16+4g+(j-4)
// ---------------------------------------------------------------------------
// Prep: weights -> bf16 fragment order (verified rounds 2-9).
//   W0a: frag 0..15 (ks*8+nt)   W0b: 16..23 (k2*2+ot)
//   W1a: 24..47 (ks*8+nt)       W1b: 48..55 (k2*2+ot)
// ---------------------------------------------------------------------------
__global__ __launch_bounds__(64) void prep_kernel(
    const float* __restrict__ W0a, const float* __restrict__ W0b,
    const float* __restrict__ W1a, const float* __restrict__ W1b,
    bf16x8* __restrict__ frag)
{
    const int fid = blockIdx.x, l = threadIdx.x, c = l & 15, g = l >> 4;
    const float* W; int N, ks, nt;
    if (fid < 16)      { W = W0a; N = 128; ks = fid >> 3;        nt = fid & 7; }
    else if (fid < 24) { W = W0b; N = 32;  ks = (fid - 16) >> 1; nt = (fid - 16) & 1; }
    else if (fid < 48) { W = W1a; N = 128; ks = (fid - 24) >> 3; nt = (fid - 24) & 7; }
    else               { W = W1b; N = 32;  ks = (fid - 48) >> 1; nt = (fid - 48) & 1; }
    bf16x8 f;
    #pragma unroll
    for (int j = 0; j < 8; ++j) {
        const int k = 32 * ks + ((j < 4) ? (4 * g + j) : (16 + 4 * g + (j - 4)));
        f[j] = f2bf(W[k * N + 16 * nt + c]);
    }
    frag[fid * 64 + l] = f;
}

// ---------------------------------------------------------------------------
// Fused kernel: r7 structure (4 waves / 256 rows, LDS weights W0->W1 union).
// vs r7: (1) T14 W1 reg-prefetch after B1 (dead by B3 -> no phase-B pressure);
// (2) tile-order topk/wts via __shfl (12 fewer VMEM/wave); (3) xf2 gather
// moved between B2/B3 to overlap W1 ds_writes; (4) s_setprio on MFMA phases.
// Blend reads own out0 from LDS (r7-style) to keep acc2a dead in phase B.
// ---------------------------------------------------------------------------
__global__ __launch_bounds__(256, 3) void fused_kernel(
    const float* __restrict__ x, const int* __restrict__ topk,
    const float* __restrict__ wts,
    const float* __restrict__ b0a, const float* __restrict__ b0b,
    const float* __restrict__ b1a, const float* __restrict__ b1b,
    const bf16x8* __restrict__ frag,
    float* __restrict__ out)
{
    const int b = blockIdx.x;
    const int bb = b * RPB;
    const int tid = threadIdx.x, wv = tid >> 6, l = tid & 63, c = l & 15, g = l >> 4;

    __shared__ __align__(16) short frag_lds[32 * 64 * 8];    // 32 KB
    __shared__ __align__(16) short out0_lds[257 * LSTRIDE];  // 18.5 KB
    __shared__ int wtot[4];

    #define LDSF(fl) (*(const bf16x8*)&frag_lds[(((fl) * 64) + l) * 8])

    // --- stage W0 frags (fid 0..23 -> local 0..23): 24KB, 6 x 16B/thread ---
    #pragma unroll
    for (int i = 0; i < 6; ++i) {
        const int e = tid + i * 256;      // e < 1536
        *(f32x4*)&frag_lds[e * 8] = *(const f32x4*)&frag[e];
    }

    // --- own-row tid-order loads: masks + weight (shuffled to tile order later) ---
    const int t = bb + tid;
    const int2 tko = ((const int2*)topk)[t];
    const bool m0o = (tko.x == 0) || (tko.y == 0);
    const bool m1o = (tko.x == 1) || (tko.y == 1);
    const int  mo_own   = (m0o ? 1 : 0) | (m1o ? 2 : 0);
    const float wgt_own = wts[(size_t)t * 2];

    // --- wave-local inclusive cummax of (mask0 ? t : 0) ---
    int s = m0o ? t : 0;
    #pragma unroll
    for (int off = 1; off < 64; off <<= 1) {
        int u = __shfl_up(s, off, 64);
        if (l >= off) s = max(s, u);
    }
    if (l == 63) wtot[wv] = s;

    // --- backward scan for p = last mask0 row < bb (input-only) ---
    int p = 0;
    for (int base = bb - 64; base >= 0; base -= 64) {
        const int2 tkq = ((const int2*)topk)[base + l];
        const bool mm = (tkq.x == 0) || (tkq.y == 0);
        const unsigned long long bal = __ballot(mm);
        if (bal) { p = base + 63 - __clzll(bal); break; }
    }
    const int2 tkp = ((const int2*)topk)[p];
    const bool m0p = (tkp.x == 0) || (tkp.y == 0);

    // --- x fragments: own 4 tiles (+ p-row on wave 3), the only x reads ---
    bf16x8 xf[4][2];
    #pragma unroll
    for (int rt = 0; rt < 4; ++rt) {
        const int row = bb + wv * 64 + rt * 16 + c;
        const float* xr = x + (size_t)row * 64;
        #pragma unroll
        for (int ks = 0; ks < 2; ++ks) {
            f32x4 a  = *(const f32x4*)(xr + 32 * ks + 4 * g);
            f32x4 b2 = *(const f32x4*)(xr + 32 * ks + 16 + 4 * g);
            #pragma unroll
            for (int j = 0; j < 4; ++j) { xf[rt][ks][j] = f2bf(a[j]); xf[rt][ks][4 + j] = f2bf(b2[j]); }
        }
    }
    bf16x8 xfp[2];
    if (wv == 3) {
        const float* xp = x + (size_t)p * 64;
        #pragma unroll
        for (int ks = 0; ks < 2; ++ks) {
            f32x4 a  = *(const f32x4*)(xp + 32 * ks + 4 * g);
            f32x4 b2 = *(const f32x4*)(xp + 32 * ks + 16 + 4 * g);
            #pragma unroll
            for (int j = 0; j < 4; ++j) { xfp[ks][j] = f2bf(a[j]); xfp[ks][4 + j] = f2bf(b2[j]); }
        }
    }

    __syncthreads();   // B1: W0 staged; wtot visible

    // --- T14: issue W1 frag loads NOW (landed by B2; dead after B2->B3 write) ---
    f32x4 w1pre[8];
    #pragma unroll
    for (int i = 0; i < 8; ++i)
        w1pre[i] = *(const f32x4*)&frag[24 * 64 + tid + i * 256];
    __builtin_amdgcn_sched_barrier(0);   // pin: loads issue before phase A

    // --- per-row global inclusive cummax ---
    int pre = 0;
    #pragma unroll
    for (int w2 = 0; w2 < 4; ++w2)
        if (w2 < wv) pre = max(pre, wtot[w2]);
    const int s_full = max(pre, s);

    // ---- phase A: MLP0, k2-outer (frags ds_read once, 4 tiles share) ----
    f32x4 acc2a[4][2];
    {
        f32x4 bi0 = *(const f32x4*)(b0b + 4 * g);
        f32x4 bi1 = *(const f32x4*)(b0b + 16 + 4 * g);
        #pragma unroll
        for (int rt = 0; rt < 4; ++rt) { acc2a[rt][0] = bi0; acc2a[rt][1] = bi1; }
    }
    __builtin_amdgcn_s_setprio(1);
    #pragma unroll
    for (int k2 = 0; k2 < 4; ++k2) {
        const bf16x8 fa00 = LDSF(0 * 8 + 2 * k2 + 0);
        const bf16x8 fa01 = LDSF(0 * 8 + 2 * k2 + 1);
        const bf16x8 fa10 = LDSF(1 * 8 + 2 * k2 + 0);
        const bf16x8 fa11 = LDSF(1 * 8 + 2 * k2 + 1);
        const bf16x8 fb0  = LDSF(16 + 2 * k2 + 0);
        const bf16x8 fb1  = LDSF(16 + 2 * k2 + 1);
        const f32x4 bi0 = *(const f32x4*)(b0a + 16 * (2 * k2 + 0) + 4 * g);
        const f32x4 bi1 = *(const f32x4*)(b0a + 16 * (2 * k2 + 1) + 4 * g);
        #pragma unroll
        for (int rt = 0; rt < 4; ++rt) {
            f32x4 a10 = bi0, a11 = bi1;
            a10 = MFMA(fa00, xf[rt][0], a10);
            a10 = MFMA(fa10, xf[rt][1], a10);
            a11 = MFMA(fa01, xf[rt][0], a11);
            a11 = MFMA(fa11, xf[rt][1], a11);
            bf16x8 hf;
            #pragma unroll
            for (int j = 0; j < 8; ++j)
                hf[j] = f2bf(fmaxf((j < 4 ? a10 : a11)[j & 3], 0.0f));
            acc2a[rt][0] = MFMA(fb0, hf, acc2a[rt][0]);
            acc2a[rt][1] = MFMA(fb1, hf, acc2a[rt][1]);
        }
    }
    __builtin_amdgcn_s_setprio(0);

    // --- store own tiles (masked, via shuffled mask) to out0 LDS ---
    #pragma unroll
    for (int rt = 0; rt < 4; ++rt) {
        const int slot = wv * 64 + rt * 16 + c;
        const bool m0 = (__shfl(mo_own, rt * 16 + c, 64) & 1);
        #pragma unroll
        for (int ot = 0; ot < 2; ++ot) {
            bf16x4 v;
            #pragma unroll
            for (int j = 0; j < 4; ++j) v[j] = f2bf(m0 ? acc2a[rt][ot][j] : 0.0f);
            *(bf16x4*)(&out0_lds[slot * LSTRIDE + 16 * ot + 4 * g]) = v;
        }
    }

    // --- wave 3: p-row tile -> slot 256 ---
    if (wv == 3) {
        f32x4 accp[2];
        accp[0] = *(const f32x4*)(b0b + 4 * g);
        accp[1] = *(const f32x4*)(b0b + 16 + 4 * g);
        #pragma unroll
        for (int k2 = 0; k2 < 4; ++k2) {
            const bf16x8 fa00 = LDSF(0 * 8 + 2 * k2 + 0);
            const bf16x8 fa01 = LDSF(0 * 8 + 2 * k2 + 1);
            const bf16x8 fa10 = LDSF(1 * 8 + 2 * k2 + 0);
            const bf16x8 fa11 = LDSF(1 * 8 + 2 * k2 + 1);
            const bf16x8 fb0  = LDSF(16 + 2 * k2 + 0);
            const bf16x8 fb1  = LDSF(16 + 2 * k2 + 1);
            f32x4 a10 = *(const f32x4*)(b0a + 16 * (2 * k2 + 0) + 4 * g);
            f32x4 a11 = *(const f32x4*)(b0a + 16 * (2 * k2 + 1) + 4 * g);
            a10 = MFMA(fa00, xfp[0], a10);
            a10 = MFMA(fa10, xfp[1], a10);
            a11 = MFMA(fa01, xfp[0], a11);
            a11 = MFMA(fa11, xfp[1], a11);
            bf16x8 hf;
            #pragma unroll
            for (int j = 0; j < 8; ++j)
                hf[j] = f2bf(fmaxf((j < 4 ? a10 : a11)[j & 3], 0.0f));
            accp[0] = MFMA(fb0, hf, accp[0]);
            accp[1] = MFMA(fb1, hf, accp[1]);
        }
        if (c == 0) {
            #pragma unroll
            for (int ot = 0; ot < 2; ++ot) {
                bf16x4 v;
                #pragma unroll
                for (int j = 0; j < 4; ++j) v[j] = f2bf(m0p ? accp[ot][j] : 0.0f);
                *(bf16x4*)(&out0_lds[256 * LSTRIDE + 16 * ot + 4 * g]) = v;
            }
        }
    }

    __syncthreads();   // B2: out0 complete; all W0 frag reads done

    // --- gather filled frags first (out0 ready at B2; overlaps W1 ds_writes) ---
    bf16x8 xf2[4];
    #pragma unroll
    for (int rt = 0; rt < 4; ++rt) {
        const int sF = __shfl(s_full, rt * 16 + c, 64);
        const int slot = (sF > 0) ? (sF - bb) : 256;
        const short* fr = &out0_lds[slot * LSTRIDE];
        bf16x4 fa_ = *(const bf16x4*)(fr + 4 * g);
        bf16x4 fb_ = *(const bf16x4*)(fr + 16 + 4 * g);
        #pragma unroll
        for (int j = 0; j < 4; ++j) { xf2[rt][j] = fa_[j]; xf2[rt][4 + j] = fb_[j]; }
    }

    // --- write W1 frags from prefetch registers (loads landed during A) ---
    #pragma unroll
    for (int i = 0; i < 8; ++i)
        *(f32x4*)&frag_lds[(tid + i * 256) * 8] = w1pre[i];

    __syncthreads();   // B3: W1 frags staged

    // ---- phase B: MLP1, k2-outer ----
    f32x4 acc2b[4][2];
    {
        f32x4 bi0 = *(const f32x4*)(b1b + 4 * g);
        f32x4 bi1 = *(const f32x4*)(b1b + 16 + 4 * g);
        #pragma unroll
        for (int rt = 0; rt < 4; ++rt) { acc2b[rt][0] = bi0; acc2b[rt][1] = bi1; }
    }
    __builtin_amdgcn_s_setprio(1);
    #pragma unroll
    for (int k2 = 0; k2 < 4; ++k2) {
        const bf16x8 fa00 = LDSF(0 * 8 + 2 * k2 + 0);   // W1a local 0..23
        const bf16x8 fa01 = LDSF(0 * 8 + 2 * k2 + 1);
        const bf16x8 fa10 = LDSF(1 * 8 + 2 * k2 + 0);
        const bf16x8 fa11 = LDSF(1 * 8 + 2 * k2 + 1);
        const bf16x8 fa20 = LDSF(2 * 8 + 2 * k2 + 0);
        const bf16x8 fa21 = LDSF(2 * 8 + 2 * k2 + 1);
        const bf16x8 fb0  = LDSF(24 + 2 * k2 + 0);      // W1b local 24..31
        const bf16x8 fb1  = LDSF(24 + 2 * k2 + 1);
        const f32x4 bi0 = *(const f32x4*)(b1a + 16 * (2 * k2 + 0) + 4 * g);
        const f32x4 bi1 = *(const f32x4*)(b1a + 16 * (2 * k2 + 1) + 4 * g);
        #pragma unroll
        for (int rt = 0; rt < 4; ++rt) {
            f32x4 a10 = bi0, a11 = bi1;
            a10 = MFMA(fa00, xf[rt][0], a10);
            a10 = MFMA(fa10, xf[rt][1], a10);
            a10 = MFMA(fa20, xf2[rt], a10);
            a11 = MFMA(fa01, xf[rt][0], a11);
            a11 = MFMA(fa11, xf[rt][1], a11);
            a11 = MFMA(fa21, xf2[rt], a11);
            bf16x8 hf;
            #pragma unroll
            for (int j = 0; j < 8; ++j)
                hf[j] = f2bf(fmaxf((j < 4 ? a10 : a11)[j & 3], 0.0f));
            acc2b[rt][0] = MFMA(fb0, hf, acc2b[rt][0]);
            acc2b[rt][1] = MFMA(fb1, hf, acc2b[rt][1]);
        }
    }
    __builtin_amdgcn_s_setprio(0);

    // --- blend + store: own out0 re-read from LDS (keeps acc2a dead here) ---
    #pragma unroll
    for (int rt = 0; rt < 4; ++rt) {
        const int slot = wv * 64 + rt * 16 + c;
        const int row = bb + slot;
        const int mo   = __shfl(mo_own, rt * 16 + c, 64);
        const float w  = __shfl(wgt_own, rt * 16 + c, 64);
        const float wc = 1.0f - w;
        const bool m1 = mo & 2;
        #pragma unroll
        for (int ot = 0; ot < 2; ++ot) {
            bf16x4 oa = *(const bf16x4*)(&out0_lds[slot * LSTRIDE + 16 * ot + 4 * g]);
            f32x4 r;
            #pragma unroll
            for (int j = 0; j < 4; ++j) {
                const float e1 = m1 ? acc2b[rt][ot][j] : 0.0f;
                r[j] = w * bf2f(oa[j]) + wc * e1;
            }
            *(f32x4*)(out + (size_t)row * 32 + 16 * ot + 4 * g) = r;
        }
    }
    #undef LDSF
}

// ---------------------------------------------------------------------------
extern "C" void kernel_launch(void* const* d_in, const int* in_sizes, int n_in,
                              void* d_out, int out_size, void* d_ws, size_t ws_size,
                              hipStream_t stream)
{
    const float* x    = (const float*)d_in[0];
    const int*   topk = (const int*)  d_in[1];
    const float* wts  = (const float*)d_in[2];
    const float* W0a  = (const float*)d_in[3];
    const float* b0a  = (const float*)d_in[4];
    const float* W0b  = (const float*)d_in[5];
    const float* b0b  = (const float*)d_in[6];
    const float* W1a  = (const float*)d_in[7];
    const float* b1a  = (const float*)d_in[8];
    const float* W1b  = (const float*)d_in[9];
    const float* b1b  = (const float*)d_in[10];
    float* out = (float*)d_out;

    bf16x8* frag = (bf16x8*)d_ws;   // 56 KiB

    prep_kernel<<<dim3(56), dim3(64), 0, stream>>>(W0a, W0b, W1a, W1b, frag);
    fused_kernel<<<dim3(NCHUNK), dim3(256), 0, stream>>>(
        x, topk, wts, b0a, b0b, b1a, b1b, frag, out);
}

// Round 11
// 137.203 us; speedup vs baseline: 1.2613x; 1.1310x over previous
//
#include <hip/hip_runtime.h>
#include <hip/hip_bf16.h>

#define TROWS 1048576
#define RPB   256                    // rows per block (chunk)
#define NCHUNK (TROWS / RPB)         // 4096
#define LSTRIDE 36                   // out0 LDS row stride in shorts (72 B)

typedef float f32x4  __attribute__((ext_vector_type(4)));
typedef short bf16x8 __attribute__((ext_vector_type(8)));
typedef short bf16x4 __attribute__((ext_vector_type(4)));

#define MFMA(a, b, c) __builtin_amdgcn_mfma_f32_16x16x32_bf16(a, b, c, 0, 0, 0)

__device__ __forceinline__ short f2bf(float v) {
    __hip_bfloat16 b = __float2bfloat16(v);
    return __builtin_bit_cast(short, b);
}
__device__ __forceinline__ float bf2f(short s) {
    unsigned u = ((unsigned)(unsigned short)s) << 16;
    return __builtin_bit_cast(float, u);
}

// k-map for ALL A/B fragments: kappa(g,j) = j<4 ? 4g+j : 16+4g+(j-4)
// ---------------------------------------------------------------------------
// Prep: weights -> bf16 fragment order (verified rounds 2-10).
//   W0a: frag 0..15 (ks*8+nt)   W0b: 16..23 (k2*2+ot)
//   W1a: 24..47 (ks*8+nt)       W1b: 48..55 (k2*2+ot)
// ---------------------------------------------------------------------------
__global__ __launch_bounds__(64) void prep_kernel(
    const float* __restrict__ W0a, const float* __restrict__ W0b,
    const float* __restrict__ W1a, const float* __restrict__ W1b,
    bf16x8* __restrict__ frag)
{
    const int fid = blockIdx.x, l = threadIdx.x, c = l & 15, g = l >> 4;
    const float* W; int N, ks, nt;
    if (fid < 16)      { W = W0a; N = 128; ks = fid >> 3;        nt = fid & 7; }
    else if (fid < 24) { W = W0b; N = 32;  ks = (fid - 16) >> 1; nt = (fid - 16) & 1; }
    else if (fid < 48) { W = W1a; N = 128; ks = (fid - 24) >> 3; nt = (fid - 24) & 7; }
    else               { W = W1b; N = 32;  ks = (fid - 48) >> 1; nt = (fid - 48) & 1; }
    bf16x8 f;
    #pragma unroll
    for (int j = 0; j < 8; ++j) {
        const int k = 32 * ks + ((j < 4) ? (4 * g + j) : (16 + 4 * g + (j - 4)));
        f[j] = f2bf(W[k * N + 16 * nt + c]);
    }
    frag[fid * 64 + l] = f;
}

// ---------------------------------------------------------------------------
// Fused kernel: r7 structure exactly (4 waves / 256 rows, LDS weights W0->W1
// union, direct W1 staging after B2 — NO reg-prefetch: r9/r10 proved the
// unified VGPR+AGPR budget at 3 waves/EU cannot absorb +32 regs without
// scratch spill). Register-neutral additions vs r7: (1) tile-order topk/wts
// via __shfl from tid-order regs; (2) xf2 gather placed before the W1
// ds_writes so out0 ds_reads overlap the W1 global-load latency;
// (3) s_setprio around MFMA clusters.
// ---------------------------------------------------------------------------
__global__ __launch_bounds__(256, 3) void fused_kernel(
    const float* __restrict__ x, const int* __restrict__ topk,
    const float* __restrict__ wts,
    const float* __restrict__ b0a, const float* __restrict__ b0b,
    const float* __restrict__ b1a, const float* __restrict__ b1b,
    const bf16x8* __restrict__ frag,
    float* __restrict__ out)
{
    const int b = blockIdx.x;
    const int bb = b * RPB;
    const int tid = threadIdx.x, wv = tid >> 6, l = tid & 63, c = l & 15, g = l >> 4;

    __shared__ __align__(16) short frag_lds[32 * 64 * 8];    // 32 KB
    __shared__ __align__(16) short out0_lds[257 * LSTRIDE];  // 18.5 KB
    __shared__ int wtot[4];

    #define LDSF(fl) (*(const bf16x8*)&frag_lds[(((fl) * 64) + l) * 8])

    // --- stage W0 frags (fid 0..23 -> local 0..23): 24KB, 6 x 16B/thread ---
    #pragma unroll
    for (int i = 0; i < 6; ++i) {
        const int e = tid + i * 256;      // e < 1536
        *(f32x4*)&frag_lds[e * 8] = *(const f32x4*)&frag[e];
    }

    // --- own-row tid-order loads: masks + weight (shuffled to tile order later) ---
    const int t = bb + tid;
    const int2 tko = ((const int2*)topk)[t];
    const bool m0o = (tko.x == 0) || (tko.y == 0);
    const bool m1o = (tko.x == 1) || (tko.y == 1);
    const int  mo_own   = (m0o ? 1 : 0) | (m1o ? 2 : 0);
    const float wgt_own = wts[(size_t)t * 2];

    // --- wave-local inclusive cummax of (mask0 ? t : 0) ---
    int s = m0o ? t : 0;
    #pragma unroll
    for (int off = 1; off < 64; off <<= 1) {
        int u = __shfl_up(s, off, 64);
        if (l >= off) s = max(s, u);
    }
    if (l == 63) wtot[wv] = s;

    // --- backward scan for p = last mask0 row < bb (input-only) ---
    int p = 0;
    for (int base = bb - 64; base >= 0; base -= 64) {
        const int2 tkq = ((const int2*)topk)[base + l];
        const bool mm = (tkq.x == 0) || (tkq.y == 0);
        const unsigned long long bal = __ballot(mm);
        if (bal) { p = base + 63 - __clzll(bal); break; }
    }
    const int2 tkp = ((const int2*)topk)[p];
    const bool m0p = (tkp.x == 0) || (tkp.y == 0);

    // --- x fragments: own 4 tiles (+ p-row on wave 3), the only x reads ---
    bf16x8 xf[4][2];
    #pragma unroll
    for (int rt = 0; rt < 4; ++rt) {
        const int row = bb + wv * 64 + rt * 16 + c;
        const float* xr = x + (size_t)row * 64;
        #pragma unroll
        for (int ks = 0; ks < 2; ++ks) {
            f32x4 a  = *(const f32x4*)(xr + 32 * ks + 4 * g);
            f32x4 b2 = *(const f32x4*)(xr + 32 * ks + 16 + 4 * g);
            #pragma unroll
            for (int j = 0; j < 4; ++j) { xf[rt][ks][j] = f2bf(a[j]); xf[rt][ks][4 + j] = f2bf(b2[j]); }
        }
    }
    bf16x8 xfp[2];
    if (wv == 3) {
        const float* xp = x + (size_t)p * 64;
        #pragma unroll
        for (int ks = 0; ks < 2; ++ks) {
            f32x4 a  = *(const f32x4*)(xp + 32 * ks + 4 * g);
            f32x4 b2 = *(const f32x4*)(xp + 32 * ks + 16 + 4 * g);
            #pragma unroll
            for (int j = 0; j < 4; ++j) { xfp[ks][j] = f2bf(a[j]); xfp[ks][4 + j] = f2bf(b2[j]); }
        }
    }

    __syncthreads();   // B1: W0 staged; wtot visible

    // --- per-row global inclusive cummax ---
    int pre = 0;
    #pragma unroll
    for (int w2 = 0; w2 < 4; ++w2)
        if (w2 < wv) pre = max(pre, wtot[w2]);
    const int s_full = max(pre, s);

    // ---- phase A: MLP0, k2-outer (frags ds_read once, 4 tiles share) ----
    f32x4 acc2a[4][2];
    {
        f32x4 bi0 = *(const f32x4*)(b0b + 4 * g);
        f32x4 bi1 = *(const f32x4*)(b0b + 16 + 4 * g);
        #pragma unroll
        for (int rt = 0; rt < 4; ++rt) { acc2a[rt][0] = bi0; acc2a[rt][1] = bi1; }
    }
    __builtin_amdgcn_s_setprio(1);
    #pragma unroll
    for (int k2 = 0; k2 < 4; ++k2) {
        const bf16x8 fa00 = LDSF(0 * 8 + 2 * k2 + 0);
        const bf16x8 fa01 = LDSF(0 * 8 + 2 * k2 + 1);
        const bf16x8 fa10 = LDSF(1 * 8 + 2 * k2 + 0);
        const bf16x8 fa11 = LDSF(1 * 8 + 2 * k2 + 1);
        const bf16x8 fb0  = LDSF(16 + 2 * k2 + 0);
        const bf16x8 fb1  = LDSF(16 + 2 * k2 + 1);
        const f32x4 bi0 = *(const f32x4*)(b0a + 16 * (2 * k2 + 0) + 4 * g);
        const f32x4 bi1 = *(const f32x4*)(b0a + 16 * (2 * k2 + 1) + 4 * g);
        #pragma unroll
        for (int rt = 0; rt < 4; ++rt) {
            f32x4 a10 = bi0, a11 = bi1;
            a10 = MFMA(fa00, xf[rt][0], a10);
            a10 = MFMA(fa10, xf[rt][1], a10);
            a11 = MFMA(fa01, xf[rt][0], a11);
            a11 = MFMA(fa11, xf[rt][1], a11);
            bf16x8 hf;
            #pragma unroll
            for (int j = 0; j < 8; ++j)
                hf[j] = f2bf(fmaxf((j < 4 ? a10 : a11)[j & 3], 0.0f));
            acc2a[rt][0] = MFMA(fb0, hf, acc2a[rt][0]);
            acc2a[rt][1] = MFMA(fb1, hf, acc2a[rt][1]);
        }
    }
    __builtin_amdgcn_s_setprio(0);

    // --- store own tiles (masked, via shuffled mask) to out0 LDS ---
    #pragma unroll
    for (int rt = 0; rt < 4; ++rt) {
        const int slot = wv * 64 + rt * 16 + c;
        const bool m0 = (__shfl(mo_own, rt * 16 + c, 64) & 1);
        #pragma unroll
        for (int ot = 0; ot < 2; ++ot) {
            bf16x4 v;
            #pragma unroll
            for (int j = 0; j < 4; ++j) v[j] = f2bf(m0 ? acc2a[rt][ot][j] : 0.0f);
            *(bf16x4*)(&out0_lds[slot * LSTRIDE + 16 * ot + 4 * g]) = v;
        }
    }

    // --- wave 3: p-row tile -> slot 256 ---
    if (wv == 3) {
        f32x4 accp[2];
        accp[0] = *(const f32x4*)(b0b + 4 * g);
        accp[1] = *(const f32x4*)(b0b + 16 + 4 * g);
        #pragma unroll
        for (int k2 = 0; k2 < 4; ++k2) {
            const bf16x8 fa00 = LDSF(0 * 8 + 2 * k2 + 0);
            const bf16x8 fa01 = LDSF(0 * 8 + 2 * k2 + 1);
            const bf16x8 fa10 = LDSF(1 * 8 + 2 * k2 + 0);
            const bf16x8 fa11 = LDSF(1 * 8 + 2 * k2 + 1);
            const bf16x8 fb0  = LDSF(16 + 2 * k2 + 0);
            const bf16x8 fb1  = LDSF(16 + 2 * k2 + 1);
            f32x4 a10 = *(const f32x4*)(b0a + 16 * (2 * k2 + 0) + 4 * g);
            f32x4 a11 = *(const f32x4*)(b0a + 16 * (2 * k2 + 1) + 4 * g);
            a10 = MFMA(fa00, xfp[0], a10);
            a10 = MFMA(fa10, xfp[1], a10);
            a11 = MFMA(fa01, xfp[0], a11);
            a11 = MFMA(fa11, xfp[1], a11);
            bf16x8 hf;
            #pragma unroll
            for (int j = 0; j < 8; ++j)
                hf[j] = f2bf(fmaxf((j < 4 ? a10 : a11)[j & 3], 0.0f));
            accp[0] = MFMA(fb0, hf, accp[0]);
            accp[1] = MFMA(fb1, hf, accp[1]);
        }
        if (c == 0) {
            #pragma unroll
            for (int ot = 0; ot < 2; ++ot) {
                bf16x4 v;
                #pragma unroll
                for (int j = 0; j < 4; ++j) v[j] = f2bf(m0p ? accp[ot][j] : 0.0f);
                *(bf16x4*)(&out0_lds[256 * LSTRIDE + 16 * ot + 4 * g]) = v;
            }
        }
    }

    __syncthreads();   // B2: out0 complete; all W0 frag reads done

    // --- gather filled frags first (out0 ready; ds_reads overlap W1 loads) ---
    bf16x8 xf2[4];
    #pragma unroll
    for (int rt = 0; rt < 4; ++rt) {
        const int sF = __shfl(s_full, rt * 16 + c, 64);
        const int slot = (sF > 0) ? (sF - bb) : 256;
        const short* fr = &out0_lds[slot * LSTRIDE];
        bf16x4 fa_ = *(const bf16x4*)(fr + 4 * g);
        bf16x4 fb_ = *(const bf16x4*)(fr + 16 + 4 * g);
        #pragma unroll
        for (int j = 0; j < 4; ++j) { xf2[rt][j] = fa_[j]; xf2[rt][4 + j] = fb_[j]; }
    }

    // --- stage W1 frags (fid 24..55 -> local 0..31): 32KB, direct (r7 style) ---
    #pragma unroll
    for (int i = 0; i < 8; ++i) {
        const int e = tid + i * 256;      // e < 2048
        *(f32x4*)&frag_lds[e * 8] = *(const f32x4*)&frag[24 * 64 + e];
    }

    __syncthreads();   // B3: W1 frags staged

    // ---- phase B: MLP1, k2-outer ----
    f32x4 acc2b[4][2];
    {
        f32x4 bi0 = *(const f32x4*)(b1b + 4 * g);
        f32x4 bi1 = *(const f32x4*)(b1b + 16 + 4 * g);
        #pragma unroll
        for (int rt = 0; rt < 4; ++rt) { acc2b[rt][0] = bi0; acc2b[rt][1] = bi1; }
    }
    __builtin_amdgcn_s_setprio(1);
    #pragma unroll
    for (int k2 = 0; k2 < 4; ++k2) {
        const bf16x8 fa00 = LDSF(0 * 8 + 2 * k2 + 0);   // W1a local 0..23
        const bf16x8 fa01 = LDSF(0 * 8 + 2 * k2 + 1);
        const bf16x8 fa10 = LDSF(1 * 8 + 2 * k2 + 0);
        const bf16x8 fa11 = LDSF(1 * 8 + 2 * k2 + 1);
        const bf16x8 fa20 = LDSF(2 * 8 + 2 * k2 + 0);
        const bf16x8 fa21 = LDSF(2 * 8 + 2 * k2 + 1);
        const bf16x8 fb0  = LDSF(24 + 2 * k2 + 0);      // W1b local 24..31
        const bf16x8 fb1  = LDSF(24 + 2 * k2 + 1);
        const f32x4 bi0 = *(const f32x4*)(b1a + 16 * (2 * k2 + 0) + 4 * g);
        const f32x4 bi1 = *(const f32x4*)(b1a + 16 * (2 * k2 + 1) + 4 * g);
        #pragma unroll
        for (int rt = 0; rt < 4; ++rt) {
            f32x4 a10 = bi0, a11 = bi1;
            a10 = MFMA(fa00, xf[rt][0], a10);
            a10 = MFMA(fa10, xf[rt][1], a10);
            a10 = MFMA(fa20, xf2[rt], a10);
            a11 = MFMA(fa01, xf[rt][0], a11);
            a11 = MFMA(fa11, xf[rt][1], a11);
            a11 = MFMA(fa21, xf2[rt], a11);
            bf16x8 hf;
            #pragma unroll
            for (int j = 0; j < 8; ++j)
                hf[j] = f2bf(fmaxf((j < 4 ? a10 : a11)[j & 3], 0.0f));
            acc2b[rt][0] = MFMA(fb0, hf, acc2b[rt][0]);
            acc2b[rt][1] = MFMA(fb1, hf, acc2b[rt][1]);
        }
    }
    __builtin_amdgcn_s_setprio(0);

    // --- blend + store: own out0 re-read from LDS (keeps acc2a dead here) ---
    #pragma unroll
    for (int rt = 0; rt < 4; ++rt) {
        const int slot = wv * 64 + rt * 16 + c;
        const int row = bb + slot;
        const int mo   = __shfl(mo_own, rt * 16 + c, 64);
        const float w  = __shfl(wgt_own, rt * 16 + c, 64);
        const float wc = 1.0f - w;
        const bool m1 = mo & 2;
        #pragma unroll
        for (int ot = 0; ot < 2; ++ot) {
            bf16x4 oa = *(const bf16x4*)(&out0_lds[slot * LSTRIDE + 16 * ot + 4 * g]);
            f32x4 r;
            #pragma unroll
            for (int j = 0; j < 4; ++j) {
                const float e1 = m1 ? acc2b[rt][ot][j] : 0.0f;
                r[j] = w * bf2f(oa[j]) + wc * e1;
            }
            *(f32x4*)(out + (size_t)row * 32 + 16 * ot + 4 * g) = r;
        }
    }
    #undef LDSF
}

// ---------------------------------------------------------------------------
extern "C" void kernel_launch(void* const* d_in, const int* in_sizes, int n_in,
                              void* d_out, int out_size, void* d_ws, size_t ws_size,
                              hipStream_t stream)
{
    const float* x    = (const float*)d_in[0];
    const int*   topk = (const int*)  d_in[1];
    const float* wts  = (const float*)d_in[2];
    const float* W0a  = (const float*)d_in[3];
    const float* b0a  = (const float*)d_in[4];
    const float* W0b  = (const float*)d_in[5];
    const float* b0b  = (const float*)d_in[6];
    const float* W1a  = (const float*)d_in[7];
    const float* b1a  = (const float*)d_in[8];
    const float* W1b  = (const float*)d_in[9];
    const float* b1b  = (const float*)d_in[10];
    float* out = (float*)d_out;

    bf16x8* frag = (bf16x8*)d_ws;   // 56 KiB

    prep_kernel<<<dim3(56), dim3(64), 0, stream>>>(W0a, W0b, W1a, W1b, frag);
    fused_kernel<<<dim3(NCHUNK), dim3(256), 0, stream>>>(
        x, topk, wts, b0a, b0b, b1a, b1b, frag, out);
}

// Round 12
// 134.258 us; speedup vs baseline: 1.2890x; 1.0219x over previous
//
#include <hip/hip_runtime.h>
#include <hip/hip_bf16.h>

#define TROWS 1048576
#define RPB   128                    // rows per block (2 tiles per wave)
#define NBLK  (TROWS / RPB)          // 8192

typedef float f32x4  __attribute__((ext_vector_type(4)));
typedef short bf16x8 __attribute__((ext_vector_type(8)));
typedef short bf16x4 __attribute__((ext_vector_type(4)));

#define MFMA(a, b, c) __builtin_amdgcn_mfma_f32_16x16x32_bf16(a, b, c, 0, 0, 0)

__device__ __forceinline__ short f2bf(float v) {
    __hip_bfloat16 b = __float2bfloat16(v);
    return __builtin_bit_cast(short, b);
}
__device__ __forceinline__ float bf2f(short s) {
    unsigned u = ((unsigned)(unsigned short)s) << 16;
    return __builtin_bit_cast(float, u);
}
// out0 table: 128 slots x 64B, 8B units XOR-swizzled by slot&7 (short index)
__device__ __forceinline__ int o0idx(int slot, int u) {
    return slot * 32 + ((u ^ (slot & 7)) << 2);
}

// k-map for ALL A/B fragments: kappa(g,j) = j<4 ? 4g+j : 16+4g+(j-4)
// ---------------------------------------------------------------------------
// Prep: weights -> bf16 fragment order (verified rounds 2-11).
//   W0a: frag 0..15 (ks*8+nt)   W0b: 16..23 (k2*2+ot)
//   W1a: 24..47 (ks*8+nt)       W1b: 48..55 (k2*2+ot)
// ---------------------------------------------------------------------------
__global__ __launch_bounds__(64) void prep_kernel(
    const float* __restrict__ W0a, const float* __restrict__ W0b,
    const float* __restrict__ W1a, const float* __restrict__ W1b,
    bf16x8* __restrict__ frag)
{
    const int fid = blockIdx.x, l = threadIdx.x, c = l & 15, g = l >> 4;
    const float* W; int N, ks, nt;
    if (fid < 16)      { W = W0a; N = 128; ks = fid >> 3;        nt = fid & 7; }
    else if (fid < 24) { W = W0b; N = 32;  ks = (fid - 16) >> 1; nt = (fid - 16) & 1; }
    else if (fid < 48) { W = W1a; N = 128; ks = (fid - 24) >> 3; nt = (fid - 24) & 7; }
    else               { W = W1b; N = 32;  ks = (fid - 48) >> 1; nt = (fid - 48) & 1; }
    bf16x8 f;
    #pragma unroll
    for (int j = 0; j < 8; ++j) {
        const int k = 32 * ks + ((j < 4) ? (4 * g + j) : (16 + 4 * g + (j - 4)));
        f[j] = f2bf(W[k * N + 16 * nt + c]);
    }
    frag[fid * 64 + l] = f;
}

// ---------------------------------------------------------------------------
// Fused kernel, occupancy-targeted: 128 rows/block, 2 tiles/wave, LDS=40960B
// (frag 32KB + out0 8KB), rolled k2 loops, <=128 regs goal (launch_bounds 4).
// slot-0 trick: if !mask0(row bb), slot 0 holds the p-row tile; blend kills
// the (zero) own-out0 of row bb. wtot folded into out0 region (pre-phase-A).
// ---------------------------------------------------------------------------
__global__ __launch_bounds__(256, 4) void fused_kernel(
    const float* __restrict__ x, const int* __restrict__ topk,
    const float* __restrict__ wts,
    const float* __restrict__ b0a, const float* __restrict__ b0b,
    const float* __restrict__ b1a, const float* __restrict__ b1b,
    const bf16x8* __restrict__ frag,
    float* __restrict__ out)
{
    const int b = blockIdx.x;
    const int bb = b * RPB;
    const int tid = threadIdx.x, wv = tid >> 6, l = tid & 63, c = l & 15, g = l >> 4;
    const int rr = l & 31;                 // scan row within wave (32 rows/wave)

    __shared__ __align__(16) short frag_lds[2048 * 16 / 2];  // 32768 B
    __shared__ __align__(16) short out0_lds[128 * 32];       // 8192 B
    int* wtot = (int*)out0_lds;            // folded: consumed before stores

    #define LDSF(fl) (*(const bf16x8*)&frag_lds[(((fl) * 64) + l) * 8])

    // --- stage W0 frags (fid 0..23): 24KB, 6 x 16B/thread ---
    #pragma unroll
    for (int i = 0; i < 6; ++i) {
        const int e = tid + i * 256;
        *(f32x4*)&frag_lds[e * 8] = *(const f32x4*)&frag[e];
    }

    // --- scan rows: wave wv owns rows bb+wv*32 .. +31 (lanes 32-63 duplicate) ---
    const int srow = bb + wv * 32 + rr;
    const int2 tko = ((const int2*)topk)[srow];
    const bool m0o = (tko.x == 0) || (tko.y == 0);
    const bool m1o = (tko.x == 1) || (tko.y == 1);
    const int  mo_own   = (m0o ? 1 : 0) | (m1o ? 2 : 0);
    const float wgt_own = wts[(size_t)srow * 2];

    int s = m0o ? srow : 0;
    #pragma unroll
    for (int off = 1; off < 32; off <<= 1) {
        int u = __shfl_up(s, off, 32);
        if (rr >= off) s = max(s, u);
    }
    if (l == 31) wtot[wv] = s;

    // --- uniform mask0 of row bb (decides slot-0 usage) ---
    const int2 tk0 = ((const int2*)topk)[bb];
    const bool m0row0 = (tk0.x == 0) || (tk0.y == 0);

    // --- backward scan for p = last mask0 row < bb (input-only) ---
    int p = 0;
    for (int base = bb - 64; base >= 0; base -= 64) {
        const int2 tkq = ((const int2*)topk)[base + l];
        const bool mm = (tkq.x == 0) || (tkq.y == 0);
        const unsigned long long bal = __ballot(mm);
        if (bal) { p = base + 63 - __clzll(bal); break; }
    }
    const int2 tkp = ((const int2*)topk)[p];
    const bool m0p = (tkp.x == 0) || (tkp.y == 0);

    // --- x fragments: 2 tiles/wave (+ p-row on wave 3) ---
    bf16x8 xf[2][2];
    #pragma unroll
    for (int rt = 0; rt < 2; ++rt) {
        const int row = bb + wv * 32 + rt * 16 + c;
        const float* xr = x + (size_t)row * 64;
        #pragma unroll
        for (int ks = 0; ks < 2; ++ks) {
            f32x4 a  = *(const f32x4*)(xr + 32 * ks + 4 * g);
            f32x4 b2 = *(const f32x4*)(xr + 32 * ks + 16 + 4 * g);
            #pragma unroll
            for (int j = 0; j < 4; ++j) { xf[rt][ks][j] = f2bf(a[j]); xf[rt][ks][4 + j] = f2bf(b2[j]); }
        }
    }
    bf16x8 xfp[2];
    if (wv == 3) {
        const float* xp = x + (size_t)p * 64;
        #pragma unroll
        for (int ks = 0; ks < 2; ++ks) {
            f32x4 a  = *(const f32x4*)(xp + 32 * ks + 4 * g);
            f32x4 b2 = *(const f32x4*)(xp + 32 * ks + 16 + 4 * g);
            #pragma unroll
            for (int j = 0; j < 4; ++j) { xfp[ks][j] = f2bf(a[j]); xfp[ks][4 + j] = f2bf(b2[j]); }
        }
    }

    __syncthreads();   // B1: W0 staged; wtot visible

    // --- per-row global inclusive cummax (wtot consumed HERE, pre-stores) ---
    int pre = 0;
    #pragma unroll
    for (int w2 = 0; w2 < 4; ++w2)
        if (w2 < wv) pre = max(pre, wtot[w2]);
    const int s_full = max(pre, s);

    // ---- phase A: MLP0, rolled k2 (frag transients stay bounded) ----
    f32x4 acc2a[2][2], accp[2];
    {
        f32x4 bi0 = *(const f32x4*)(b0b + 4 * g);
        f32x4 bi1 = *(const f32x4*)(b0b + 16 + 4 * g);
        acc2a[0][0] = bi0; acc2a[0][1] = bi1;
        acc2a[1][0] = bi0; acc2a[1][1] = bi1;
        accp[0] = bi0; accp[1] = bi1;
    }
    #pragma unroll 1
    for (int k2 = 0; k2 < 4; ++k2) {
        const bf16x8 fa00 = LDSF(0 * 8 + 2 * k2 + 0);
        const bf16x8 fa01 = LDSF(0 * 8 + 2 * k2 + 1);
        const bf16x8 fa10 = LDSF(1 * 8 + 2 * k2 + 0);
        const bf16x8 fa11 = LDSF(1 * 8 + 2 * k2 + 1);
        const bf16x8 fb0  = LDSF(16 + 2 * k2 + 0);
        const bf16x8 fb1  = LDSF(16 + 2 * k2 + 1);
        const f32x4 bi0 = *(const f32x4*)(b0a + 16 * (2 * k2 + 0) + 4 * g);
        const f32x4 bi1 = *(const f32x4*)(b0a + 16 * (2 * k2 + 1) + 4 * g);
        #pragma unroll
        for (int rt = 0; rt < 2; ++rt) {
            f32x4 a10 = bi0, a11 = bi1;
            a10 = MFMA(fa00, xf[rt][0], a10);
            a10 = MFMA(fa10, xf[rt][1], a10);
            a11 = MFMA(fa01, xf[rt][0], a11);
            a11 = MFMA(fa11, xf[rt][1], a11);
            bf16x8 hf;
            #pragma unroll
            for (int j = 0; j < 8; ++j)
                hf[j] = f2bf(fmaxf((j < 4 ? a10 : a11)[j & 3], 0.0f));
            acc2a[rt][0] = MFMA(fb0, hf, acc2a[rt][0]);
            acc2a[rt][1] = MFMA(fb1, hf, acc2a[rt][1]);
        }
        if (wv == 3) {                      // p-row tile shares this k2's frags
            f32x4 a10 = bi0, a11 = bi1;
            a10 = MFMA(fa00, xfp[0], a10);
            a10 = MFMA(fa10, xfp[1], a10);
            a11 = MFMA(fa01, xfp[0], a11);
            a11 = MFMA(fa11, xfp[1], a11);
            bf16x8 hf;
            #pragma unroll
            for (int j = 0; j < 8; ++j)
                hf[j] = f2bf(fmaxf((j < 4 ? a10 : a11)[j & 3], 0.0f));
            accp[0] = MFMA(fb0, hf, accp[0]);
            accp[1] = MFMA(fb1, hf, accp[1]);
        }
    }

    // --- store tiles (masked); suppress slot 0 when it belongs to p ---
    #pragma unroll
    for (int rt = 0; rt < 2; ++rt) {
        const int slot = wv * 32 + rt * 16 + c;
        const bool m0 = (__shfl(mo_own, rt * 16 + c, 64) & 1);
        const bool sk = (slot == 0) && !m0row0;
        #pragma unroll
        for (int ot = 0; ot < 2; ++ot) {
            bf16x4 v;
            #pragma unroll
            for (int j = 0; j < 4; ++j) v[j] = f2bf(m0 ? acc2a[rt][ot][j] : 0.0f);
            if (!sk) *(bf16x4*)(&out0_lds[o0idx(slot, ot * 4 + g)]) = v;
        }
    }
    // p-row -> slot 0 (only when row bb is not mask0; all c hold same row)
    if (wv == 3 && !m0row0 && c == 0) {
        #pragma unroll
        for (int ot = 0; ot < 2; ++ot) {
            bf16x4 v;
            #pragma unroll
            for (int j = 0; j < 4; ++j) v[j] = f2bf(m0p ? accp[ot][j] : 0.0f);
            *(bf16x4*)(&out0_lds[o0idx(0, ot * 4 + g)]) = v;
        }
    }

    __syncthreads();   // B2: out0 complete; W0 frag reads done

    // --- stage W1 frags (fid 24..55 -> local 0..31): 32KB via reg round-trip ---
    f32x4 w1t0 = *(const f32x4*)&frag[24 * 64 + tid + 0 * 256];
    f32x4 w1t1 = *(const f32x4*)&frag[24 * 64 + tid + 1 * 256];
    f32x4 w1t2 = *(const f32x4*)&frag[24 * 64 + tid + 2 * 256];
    f32x4 w1t3 = *(const f32x4*)&frag[24 * 64 + tid + 3 * 256];
    f32x4 w1t4 = *(const f32x4*)&frag[24 * 64 + tid + 4 * 256];
    f32x4 w1t5 = *(const f32x4*)&frag[24 * 64 + tid + 5 * 256];
    f32x4 w1t6 = *(const f32x4*)&frag[24 * 64 + tid + 6 * 256];
    f32x4 w1t7 = *(const f32x4*)&frag[24 * 64 + tid + 7 * 256];

    // gather slots resolved while loads are in flight
    int slotF[2];
    #pragma unroll
    for (int rt = 0; rt < 2; ++rt) {
        const int sF = __shfl(s_full, rt * 16 + c, 64);
        slotF[rt] = (sF > 0) ? (sF - bb) : 0;
    }

    *(f32x4*)&frag_lds[(tid + 0 * 256) * 8] = w1t0;
    *(f32x4*)&frag_lds[(tid + 1 * 256) * 8] = w1t1;
    *(f32x4*)&frag_lds[(tid + 2 * 256) * 8] = w1t2;
    *(f32x4*)&frag_lds[(tid + 3 * 256) * 8] = w1t3;
    *(f32x4*)&frag_lds[(tid + 4 * 256) * 8] = w1t4;
    *(f32x4*)&frag_lds[(tid + 5 * 256) * 8] = w1t5;
    *(f32x4*)&frag_lds[(tid + 6 * 256) * 8] = w1t6;
    *(f32x4*)&frag_lds[(tid + 7 * 256) * 8] = w1t7;

    __syncthreads();   // B3: W1 frags staged

    // ---- phase B: MLP1, rolled k2; xf2 re-gathered per k2 (transient) ----
    f32x4 acc2b[2][2];
    {
        f32x4 bi0 = *(const f32x4*)(b1b + 4 * g);
        f32x4 bi1 = *(const f32x4*)(b1b + 16 + 4 * g);
        acc2b[0][0] = bi0; acc2b[0][1] = bi1;
        acc2b[1][0] = bi0; acc2b[1][1] = bi1;
    }
    #pragma unroll 1
    for (int k2 = 0; k2 < 4; ++k2) {
        const bf16x8 fa00 = LDSF(0 * 8 + 2 * k2 + 0);   // W1a local 0..23
        const bf16x8 fa01 = LDSF(0 * 8 + 2 * k2 + 1);
        const bf16x8 fa10 = LDSF(1 * 8 + 2 * k2 + 0);
        const bf16x8 fa11 = LDSF(1 * 8 + 2 * k2 + 1);
        const bf16x8 fa20 = LDSF(2 * 8 + 2 * k2 + 0);
        const bf16x8 fa21 = LDSF(2 * 8 + 2 * k2 + 1);
        const bf16x8 fb0  = LDSF(24 + 2 * k2 + 0);      // W1b local 24..31
        const bf16x8 fb1  = LDSF(24 + 2 * k2 + 1);
        const f32x4 bi0 = *(const f32x4*)(b1a + 16 * (2 * k2 + 0) + 4 * g);
        const f32x4 bi1 = *(const f32x4*)(b1a + 16 * (2 * k2 + 1) + 4 * g);
        #pragma unroll
        for (int rt = 0; rt < 2; ++rt) {
            bf16x8 xf2;
            {
                const int sl = slotF[rt];
                bf16x4 fa_ = *(const bf16x4*)&out0_lds[o0idx(sl, g)];
                bf16x4 fb_ = *(const bf16x4*)&out0_lds[o0idx(sl, 4 + g)];
                #pragma unroll
                for (int j = 0; j < 4; ++j) { xf2[j] = fa_[j]; xf2[4 + j] = fb_[j]; }
            }
            f32x4 a10 = bi0, a11 = bi1;
            a10 = MFMA(fa00, xf[rt][0], a10);
            a10 = MFMA(fa10, xf[rt][1], a10);
            a10 = MFMA(fa20, xf2, a10);
            a11 = MFMA(fa01, xf[rt][0], a11);
            a11 = MFMA(fa11, xf[rt][1], a11);
            a11 = MFMA(fa21, xf2, a11);
            bf16x8 hf;
            #pragma unroll
            for (int j = 0; j < 8; ++j)
                hf[j] = f2bf(fmaxf((j < 4 ? a10 : a11)[j & 3], 0.0f));
            acc2b[rt][0] = MFMA(fb0, hf, acc2b[rt][0]);
            acc2b[rt][1] = MFMA(fb1, hf, acc2b[rt][1]);
        }
    }

    // --- blend + store ---
    #pragma unroll
    for (int rt = 0; rt < 2; ++rt) {
        const int slot = wv * 32 + rt * 16 + c;
        const int row = bb + slot;
        const int mo   = __shfl(mo_own, rt * 16 + c, 64);
        const float w  = __shfl(wgt_own, rt * 16 + c, 64);
        const float wc = 1.0f - w;
        const bool m1 = mo & 2;
        const bool kill = (slot == 0) && !m0row0;   // slot 0 holds p, own out0 = 0
        #pragma unroll
        for (int ot = 0; ot < 2; ++ot) {
            bf16x4 oa = *(const bf16x4*)(&out0_lds[o0idx(slot, ot * 4 + g)]);
            f32x4 r;
            #pragma unroll
            for (int j = 0; j < 4; ++j) {
                const float e0 = kill ? 0.0f : bf2f(oa[j]);
                const float e1 = m1 ? acc2b[rt][ot][j] : 0.0f;
                r[j] = w * e0 + wc * e1;
            }
            *(f32x4*)(out + (size_t)row * 32 + 16 * ot + 4 * g) = r;
        }
    }
    #undef LDSF
}

// ---------------------------------------------------------------------------
extern "C" void kernel_launch(void* const* d_in, const int* in_sizes, int n_in,
                              void* d_out, int out_size, void* d_ws, size_t ws_size,
                              hipStream_t stream)
{
    const float* x    = (const float*)d_in[0];
    const int*   topk = (const int*)  d_in[1];
    const float* wts  = (const float*)d_in[2];
    const float* W0a  = (const float*)d_in[3];
    const float* b0a  = (const float*)d_in[4];
    const float* W0b  = (const float*)d_in[5];
    const float* b0b  = (const float*)d_in[6];
    const float* W1a  = (const float*)d_in[7];
    const float* b1a  = (const float*)d_in[8];
    const float* W1b  = (const float*)d_in[9];
    const float* b1b  = (const float*)d_in[10];
    float* out = (float*)d_out;

    bf16x8* frag = (bf16x8*)d_ws;   // 56 KiB

    prep_kernel<<<dim3(56), dim3(64), 0, stream>>>(W0a, W0b, W1a, W1b, frag);
    fused_kernel<<<dim3(NBLK), dim3(256), 0, stream>>>(
        x, topk, wts, b0a, b0b, b1a, b1b, frag, out);
}